// Round 8
// baseline (379.504 us; speedup 1.0000x reference)
//
#include <hip/hip_runtime.h>
#include <math.h>

static constexpr int BT  = 512;    // batch
static constexpr int TT  = 2048;   // time steps
static constexpr int NCH = BT * 8; // 4096 chains

// f64-derived constants, cast to f32 exactly as the reference does
static constexpr float C00 = (float)(1000.0 / (1.0 - 0.09));            // D[0][0]
static constexpr float C01 = (float)((1000.0 / (1.0 - 0.09)) * 0.3);    // D[0][1]
static constexpr float C22 = (float)((1000.0 / (1.0 - 0.09)) * 0.35);   // D[2][2]
static constexpr float INV3GH = (float)(1.0 / (3.0 * (1000.0 / 2.6) + 100.0));
static constexpr float SQ3 = 1.7320508075688772f;
static constexpr float IR3 = 0.57735026918962576f;

__device__ __forceinline__ float softplus_f(float v) {
    return fmaxf(v, 0.0f) + log1pf(expf(-fabsf(v)));
}

struct F3 { float x, y, z; };

// ---------------------------------------------------------------------------
// K1: projections + damage candidate, fully coalesced via LDS x-tile.
// Block = (one b) x (32 t); thread (tl = tid>>3, p = tid&7).
// arr[g][t][lane] float4 = (d_new, De_xx, De_yy, sqrt(3)*De_xy);
// g = b>>3, lane = (b&7)*8 + p.
// ---------------------------------------------------------------------------
__global__ __launch_bounds__(256) void k_proj(
    const float* __restrict__ x, const float* __restrict__ W11,
    const float* __restrict__ W12, float4* __restrict__ arr)
{
    __shared__ __align__(16) float xs[32 * 36];    // [tl][36] padded
    __shared__ __align__(16) float w11s[16 * 36];  // [2p+h][36]
    __shared__ __align__(16) float w12d[24 * 36];  // [3p+j][36], D & sqrt3 folded
    const int tid = threadIdx.x;

    for (int i = tid; i < 512; i += 256)
        w11s[(i >> 5) * 36 + (i & 31)] = W11[i];
    for (int i = tid; i < 768; i += 256) {
        int r = i >> 5, fc = i & 31;
        int p = r / 3, j = r - p * 3;
        const float* wb = W12 + p * 96 + fc;
        float v;
        if (j == 0)      v = C00 * wb[0]  + C01 * wb[32];
        else if (j == 1) v = C01 * wb[0]  + C00 * wb[32];
        else             v = (C22 * wb[64]) * SQ3;
        w12d[r * 36 + fc] = v;
    }

    const int b  = blockIdx.x >> 6;
    const int tt = (blockIdx.x & 63) << 5;

    // stage x tile: 256 float4, perfectly coalesced
    {
        const float4* xg = (const float4*)(x + ((size_t)b * TT + tt) * 32);
        float4 val = xg[tid];
        int tl = tid >> 3, c = tid & 7;
        *(float4*)&xs[tl * 36 + c * 4] = val;
    }
    __syncthreads();

    const int tl = tid >> 3, p = tid & 7;
    const float* xr = xs + tl * 36;
    const float4* wa0 = (const float4*)(w11s + (2 * p) * 36);
    const float4* wa1 = (const float4*)(w11s + (2 * p + 1) * 36);
    const float4* wb0 = (const float4*)(w12d + (3 * p) * 36);
    const float4* wb1 = (const float4*)(w12d + (3 * p + 1) * 36);
    const float4* wb2 = (const float4*)(w12d + (3 * p + 2) * 36);

    float dn = 0.f, ds = 0.f, e0 = 0.f, e1 = 0.f, e2 = 0.f;
    #pragma unroll
    for (int c = 0; c < 8; ++c) {
        float4 xf = *(const float4*)(xr + 4 * c);
        float4 a0 = wa0[c], a1 = wa1[c];
        float4 b0 = wb0[c], b1 = wb1[c], b2 = wb2[c];
        dn = fmaf(xf.x, a0.x, dn); dn = fmaf(xf.y, a0.y, dn);
        dn = fmaf(xf.z, a0.z, dn); dn = fmaf(xf.w, a0.w, dn);
        ds = fmaf(xf.x, a1.x, ds); ds = fmaf(xf.y, a1.y, ds);
        ds = fmaf(xf.z, a1.z, ds); ds = fmaf(xf.w, a1.w, ds);
        e0 = fmaf(xf.x, b0.x, e0); e0 = fmaf(xf.y, b0.y, e0);
        e0 = fmaf(xf.z, b0.z, e0); e0 = fmaf(xf.w, b0.w, e0);
        e1 = fmaf(xf.x, b1.x, e1); e1 = fmaf(xf.y, b1.y, e1);
        e1 = fmaf(xf.z, b1.z, e1); e1 = fmaf(xf.w, b1.w, e1);
        e2 = fmaf(xf.x, b2.x, e2); e2 = fmaf(xf.y, b2.y, e2);
        e2 = fmaf(xf.z, b2.z, e2); e2 = fmaf(xf.w, b2.w, e2);
    }
    float dnp = fmaxf(dn, 0.f);
    float lam = sqrtf(fmaf(dnp, dnp, fmaf(ds, ds, 1e-12f)));
    float dnew = (0.1f * (lam - 0.01f)) / (lam * 0.09f);
    dnew = fminf(fmaxf(dnew, 0.f), 1.f);

    arr[((size_t)(b >> 3) * TT + tt + tl) * 64 + (b & 7) * 8 + p] =
        make_float4(dnew, e0, e1, e2);
}

// ---------------------------------------------------------------------------
// K2: sequential scan, LDS-DMA ring (unchanged counts) + LEAN BRANCHLESS body.
// xy channel runs sqrt(3)-scaled (q needs no 3x mul); plastic math always
// executes (f==1 exactly for elastic lanes). 4-group superblocks give
// immediate store offsets (one base advance per 32 steps).
// Output: damaged stress (xy still sqrt3-scaled), 12 B at sig[b][t][3p..].
// ---------------------------------------------------------------------------
#define GLOAD(gp, lp) \
    __builtin_amdgcn_global_load_lds( \
        (const __attribute__((address_space(1))) void*)(gp), \
        (__attribute__((address_space(3))) void*)(lp), 16, 0, 0)

struct St { float d, Pxx, Pyy, Pxy, sigY; };

__device__ __forceinline__ void scan_step(float4 v, St& s, float* o)
{
    bool loading = v.x > s.d;            // d_new > d_hist
    s.d = fmaxf(s.d, v.x);
    float sxx = v.y - s.Pxx, syy = v.z - s.Pyy, sxy = v.w - s.Pxy;
    float q = fmaf(sxy, sxy, 1e-12f);    // sxy is sqrt3-scaled: = 3*sxy_true^2
    q = fmaf(syy, syy, q);
    q = fmaf(sxx, sxx - syy, q);
    float rq  = __builtin_amdgcn_rsqf(q);
    float seq = q * rq;                  // sqrt(q)
    float dk  = fmaxf(seq - s.sigY, 0.f) * INV3GH;
    float fn  = fmaf(100.f, dk, s.sigY); // new sigY (elastic: = old)
    float f   = fminf(fn * rq, 1.f);     // elastic: exactly 1
    s.Pxx = fmaf(-f, sxx, v.y);
    s.Pyy = fmaf(-f, syy, v.z);
    s.Pxy = fmaf(-f, sxy, v.w);
    s.sigY = fn;
    float fom = f * (1.0f - s.d);
    float scale = loading ? f : fom;
    o[0] = scale * sxx; o[1] = scale * syy; o[2] = scale * sxy;
}

// K = group position in superblock (= g & 3). Reads slot K, loads slot K+3.
template<int WN, bool LD, int K>
__device__ __forceinline__ void do_group(
    const float4*& apl, float4 (&ring)[4][8][64], int lane, St& s, float* spb)
{
    asm volatile("s_waitcnt vmcnt(%0)" :: "n"(WN) : "memory");
    float4 v[8];
    #pragma unroll
    for (int j = 0; j < 8; ++j) v[j] = ring[K][j][lane];
    if (LD) {
        #pragma unroll
        for (int j = 0; j < 8; ++j)
            GLOAD(apl + (size_t)j * 64, &ring[(K + 3) & 3][j][0]);
        apl += 512;
    }
    __builtin_amdgcn_sched_barrier(0);   // pin [L-pack][S-pack] issue order
    #pragma unroll
    for (int j = 0; j < 8; ++j) {
        float o[3];
        scan_step(v[j], s, o);
        *(F3*)(spb + (size_t)(K * 8 + j) * 24) = {o[0], o[1], o[2]};
    }
}

__global__ __launch_bounds__(64) void k_scan(
    const float4* __restrict__ arr, float* __restrict__ sig)
{
    __shared__ float4 ring[4][8][64];    // 32 KiB
    const int lane = threadIdx.x;
    const float4* ap  = arr + (size_t)blockIdx.x * (TT * 64) + lane;
    const float4* apl = ap;
    const int b = blockIdx.x * 8 + (lane >> 3), p = lane & 7;
    float* sp = sig + (size_t)b * (TT * 24) + 3 * p;

    St s = {0.f, 0.f, 0.f, 0.f, 10.f};

    // prologue: DMA groups 0..2 (24 loads)
    #pragma unroll
    for (int g = 0; g < 3; ++g) {
        #pragma unroll
        for (int j = 0; j < 8; ++j)
            GLOAD(apl + (size_t)j * 64, &ring[g][j][0]);
        apl += 512;
    }

    // counts as in round 7 (16 ld + 8 st per group in flight bookkeeping):
    // g=0:16  g=1:24  g=2:32  steady:40  tail:40/40/32/24
    do_group<16, true, 0>(apl, ring, lane, s, sp);
    do_group<24, true, 1>(apl, ring, lane, s, sp);
    do_group<32, true, 2>(apl, ring, lane, s, sp);
    do_group<40, true, 3>(apl, ring, lane, s, sp);
    sp += 768;
    for (int sb = 1; sb < 63; ++sb) {
        do_group<40, true, 0>(apl, ring, lane, s, sp);
        do_group<40, true, 1>(apl, ring, lane, s, sp);
        do_group<40, true, 2>(apl, ring, lane, s, sp);
        do_group<40, true, 3>(apl, ring, lane, s, sp);
        sp += 768;
    }
    do_group<40, true,  0>(apl, ring, lane, s, sp);  // g=252 loads g=255
    do_group<40, false, 1>(apl, ring, lane, s, sp);
    do_group<32, false, 2>(apl, ring, lane, s, sp);
    do_group<24, false, 3>(apl, ring, lane, s, sp);
}

// ---------------------------------------------------------------------------
// K3: out[b][t][:] = sig_row(24) @ softplus(W2)^T, with 1/sqrt(3) folded
// into the xy weight columns (sig_xy is stored sqrt3-scaled).
// ---------------------------------------------------------------------------
__global__ __launch_bounds__(256) void k_out(
    const float* __restrict__ sig, const float* __restrict__ W2,
    float* __restrict__ out)
{
    __shared__ float w2s[144];
    int tid = threadIdx.x;
    if (tid < 144) {
        float v = softplus_f(W2[tid]);
        if ((tid % 24) % 3 == 2) v *= IR3;
        w2s[tid] = v;
    }
    __syncthreads();

    int gid = blockIdx.x * 256 + tid;          // = b*2048 + t = sig row
    const float4* sp = (const float4*)(sig + (size_t)gid * 24);
    float4 v[6];
    #pragma unroll
    for (int i = 0; i < 6; ++i) v[i] = sp[i];
    float s[24];
    #pragma unroll
    for (int i = 0; i < 6; ++i) {
        s[4*i] = v[i].x; s[4*i+1] = v[i].y; s[4*i+2] = v[i].z; s[4*i+3] = v[i].w;
    }
    float o[6];
    #pragma unroll
    for (int k = 0; k < 6; ++k) {
        float acc = 0.f;
        #pragma unroll
        for (int j = 0; j < 24; ++j) acc = fmaf(s[j], w2s[k * 24 + j], acc);
        o[k] = acc;
    }
    float2* ov = (float2*)(out + (size_t)gid * 6);
    ov[0] = make_float2(o[0], o[1]);
    ov[1] = make_float2(o[2], o[3]);
    ov[2] = make_float2(o[4], o[5]);
}

extern "C" void kernel_launch(void* const* d_in, const int* in_sizes, int n_in,
                              void* d_out, int out_size, void* d_ws, size_t ws_size,
                              hipStream_t stream)
{
    const float* x   = (const float*)d_in[0];
    const float* W11 = (const float*)d_in[1];
    const float* W12 = (const float*)d_in[2];
    const float* W2  = (const float*)d_in[3];
    float* out = (float*)d_out;

    float4* arr = (float4*)d_ws;                                    // 128 MiB
    float*  sig = (float*)((char*)d_ws + (size_t)TT * NCH * 16);    //  96 MiB

    hipLaunchKernelGGL(k_proj, dim3(BT * (TT / 32)), dim3(256), 0, stream,
                       x, W11, W12, arr);
    hipLaunchKernelGGL(k_scan, dim3(NCH / 64), dim3(64), 0, stream, arr, sig);
    hipLaunchKernelGGL(k_out,  dim3((BT * TT) / 256), dim3(256), 0, stream,
                       sig, W2, out);
}

// Round 9
// 363.797 us; speedup vs baseline: 1.0432x; 1.0432x over previous
//
#include <hip/hip_runtime.h>
#include <math.h>

static constexpr int BT  = 512;    // batch
static constexpr int TT  = 2048;   // time steps
static constexpr int NCH = BT * 8; // 4096 chains

// f64-derived constants, cast to f32 exactly as the reference does
static constexpr float C00 = (float)(1000.0 / (1.0 - 0.09));            // D[0][0]
static constexpr float C01 = (float)((1000.0 / (1.0 - 0.09)) * 0.3);    // D[0][1]
static constexpr float C22 = (float)((1000.0 / (1.0 - 0.09)) * 0.35);   // D[2][2]
static constexpr float INV3GH = (float)(1.0 / (3.0 * (1000.0 / 2.6) + 100.0));
static constexpr float SQ3 = 1.7320508075688772f;
static constexpr float IR3 = 0.57735026918962576f;

__device__ __forceinline__ float softplus_f(float v) {
    return fmaxf(v, 0.0f) + log1pf(expf(-fabsf(v)));
}

// ---------------------------------------------------------------------------
// K1: projections + damage candidate, coalesced via LDS x-tile (round-8 ver).
// arr[g][t][lane] float4 = (d_new, De_xx, De_yy, sqrt(3)*De_xy);
// g = b>>3, lane = (b&7)*8 + p.
// ---------------------------------------------------------------------------
__global__ __launch_bounds__(256) void k_proj(
    const float* __restrict__ x, const float* __restrict__ W11,
    const float* __restrict__ W12, float4* __restrict__ arr)
{
    __shared__ __align__(16) float xs[32 * 36];    // [tl][36] padded
    __shared__ __align__(16) float w11s[16 * 36];  // [2p+h][36]
    __shared__ __align__(16) float w12d[24 * 36];  // [3p+j][36], D & sqrt3 folded
    const int tid = threadIdx.x;

    for (int i = tid; i < 512; i += 256)
        w11s[(i >> 5) * 36 + (i & 31)] = W11[i];
    for (int i = tid; i < 768; i += 256) {
        int r = i >> 5, fc = i & 31;
        int p = r / 3, j = r - p * 3;
        const float* wb = W12 + p * 96 + fc;
        float v;
        if (j == 0)      v = C00 * wb[0]  + C01 * wb[32];
        else if (j == 1) v = C01 * wb[0]  + C00 * wb[32];
        else             v = (C22 * wb[64]) * SQ3;
        w12d[r * 36 + fc] = v;
    }

    const int b  = blockIdx.x >> 6;
    const int tt = (blockIdx.x & 63) << 5;

    {
        const float4* xg = (const float4*)(x + ((size_t)b * TT + tt) * 32);
        float4 val = xg[tid];
        int tl = tid >> 3, c = tid & 7;
        *(float4*)&xs[tl * 36 + c * 4] = val;
    }
    __syncthreads();

    const int tl = tid >> 3, p = tid & 7;
    const float* xr = xs + tl * 36;
    const float4* wa0 = (const float4*)(w11s + (2 * p) * 36);
    const float4* wa1 = (const float4*)(w11s + (2 * p + 1) * 36);
    const float4* wb0 = (const float4*)(w12d + (3 * p) * 36);
    const float4* wb1 = (const float4*)(w12d + (3 * p + 1) * 36);
    const float4* wb2 = (const float4*)(w12d + (3 * p + 2) * 36);

    float dn = 0.f, ds = 0.f, e0 = 0.f, e1 = 0.f, e2 = 0.f;
    #pragma unroll
    for (int c = 0; c < 8; ++c) {
        float4 xf = *(const float4*)(xr + 4 * c);
        float4 a0 = wa0[c], a1 = wa1[c];
        float4 b0 = wb0[c], b1 = wb1[c], b2 = wb2[c];
        dn = fmaf(xf.x, a0.x, dn); dn = fmaf(xf.y, a0.y, dn);
        dn = fmaf(xf.z, a0.z, dn); dn = fmaf(xf.w, a0.w, dn);
        ds = fmaf(xf.x, a1.x, ds); ds = fmaf(xf.y, a1.y, ds);
        ds = fmaf(xf.z, a1.z, ds); ds = fmaf(xf.w, a1.w, ds);
        e0 = fmaf(xf.x, b0.x, e0); e0 = fmaf(xf.y, b0.y, e0);
        e0 = fmaf(xf.z, b0.z, e0); e0 = fmaf(xf.w, b0.w, e0);
        e1 = fmaf(xf.x, b1.x, e1); e1 = fmaf(xf.y, b1.y, e1);
        e1 = fmaf(xf.z, b1.z, e1); e1 = fmaf(xf.w, b1.w, e1);
        e2 = fmaf(xf.x, b2.x, e2); e2 = fmaf(xf.y, b2.y, e2);
        e2 = fmaf(xf.z, b2.z, e2); e2 = fmaf(xf.w, b2.w, e2);
    }
    float dnp = fmaxf(dn, 0.f);
    float lam = sqrtf(fmaf(dnp, dnp, fmaf(ds, ds, 1e-12f)));
    float dnew = (0.1f * (lam - 0.01f)) / (lam * 0.09f);
    dnew = fminf(fmaxf(dnew, 0.f), 1.f);

    arr[((size_t)(b >> 3) * TT + tt + tl) * 64 + (b & 7) * 8 + p] =
        make_float4(dnew, e0, e1, e2);
}

// ---------------------------------------------------------------------------
// K2: sequential scan. LDS-DMA ring + __any elastic skip (round-7 winner)
// + chain-major output: each group's 24 output floats are contiguous 96 B
// per lane -> 6 dwordx4 store events/group (was 16), and EXACT vmcnt counts
// (steady 34) so stores get ~3 groups to retire without forcing a drain.
// sig layout: [chain][t][3], chain = blk*64 + lane; xy stays sqrt3-scaled.
// ---------------------------------------------------------------------------
#define GLOAD(gp, lp) \
    __builtin_amdgcn_global_load_lds( \
        (const __attribute__((address_space(1))) void*)(gp), \
        (__attribute__((address_space(3))) void*)(lp), 16, 0, 0)

struct St { float d, Pxx, Pyy, Pxy, sigY, sigY2; };

__device__ __forceinline__ void scan_step(float4 v, St& s, float* o)
{
    bool loading = v.x > s.d;            // d_new > d_hist
    s.d = fmaxf(s.d, v.x);
    float sxx = v.y - s.Pxx, syy = v.z - s.Pyy, sxy = v.w - s.Pxy;
    float q = fmaf(sxy, sxy, 1e-12f);    // sxy sqrt3-scaled: term = 3*sxy_true^2
    q = fmaf(syy, syy, q);
    q = fmaf(sxx, sxx - syy, q);
    float f = 1.0f;
    if (__any(q > s.sigY2)) {            // wave-uniform plastic section
        float rq  = __builtin_amdgcn_rsqf(q);
        float seq = q * rq;              // sqrt(q)
        float dk  = fmaxf(seq - s.sigY, 0.f) * INV3GH;
        float fn  = fmaf(100.f, dk, s.sigY);   // new sigY (elastic lane: old)
        f = fminf(fn * rq, 1.f);         // elastic lane: exactly 1
        s.Pxx = fmaf(-f, sxx, v.y);
        s.Pyy = fmaf(-f, syy, v.z);
        s.Pxy = fmaf(-f, sxy, v.w);
        s.sigY  = fn;
        s.sigY2 = fn * fn;
    }
    float scale = loading ? f : f * (1.0f - s.d);
    o[0] = scale * sxx; o[1] = scale * syy; o[2] = scale * sxy;
}

template<int WN, bool LD>
__device__ __forceinline__ void do_group(
    int g, const float4*& apl, float4 (&ring)[4][8][64], int lane,
    St& s, float*& spg)
{
    asm volatile("s_waitcnt vmcnt(%0)" :: "n"(WN) : "memory");
    const int slot = g & 3;
    float4 v[8];
    #pragma unroll
    for (int j = 0; j < 8; ++j) v[j] = ring[slot][j][lane];
    if (LD) {
        #pragma unroll
        for (int j = 0; j < 8; ++j)
            GLOAD(apl + (size_t)j * 64, &ring[(g + 3) & 3][j][0]);
        apl += 512;
    }
    __builtin_amdgcn_sched_barrier(0);   // pin [L-pack][S-pack] issue order
    float o[24];
    #pragma unroll
    for (int j = 0; j < 8; ++j)
        scan_step(v[j], s, &o[3 * j]);
    float4* d4 = (float4*)spg;
    d4[0] = make_float4(o[0],  o[1],  o[2],  o[3]);
    d4[1] = make_float4(o[4],  o[5],  o[6],  o[7]);
    d4[2] = make_float4(o[8],  o[9],  o[10], o[11]);
    d4[3] = make_float4(o[12], o[13], o[14], o[15]);
    d4[4] = make_float4(o[16], o[17], o[18], o[19]);
    d4[5] = make_float4(o[20], o[21], o[22], o[23]);
    spg += 24;
}

__global__ __launch_bounds__(64) void k_scan(
    const float4* __restrict__ arr, float* __restrict__ sig)
{
    __shared__ float4 ring[4][8][64];    // 32 KiB
    const int lane = threadIdx.x;
    const float4* apl = arr + (size_t)blockIdx.x * (TT * 64) + lane;
    const int chain = blockIdx.x * 64 + lane;    // = b*8+p
    float* spg = sig + (size_t)chain * (TT * 3);

    St s = {0.f, 0.f, 0.f, 0.f, 10.f, 100.f};

    // prologue: DMA groups 0..2 (24 load events)
    #pragma unroll
    for (int g = 0; g < 3; ++g) {
        #pragma unroll
        for (int j = 0; j < 8; ++j)
            GLOAD(apl + (size_t)j * 64, &ring[g][j][0]);
        apl += 512;
    }

    // Exact newer-than-L(g) event counts (8 loads + 6 stores per group):
    // g0:16  g1:22  g2:28  steady:34  tail g253:34 g254:26 g255:18
    do_group<16, true >(0, apl, ring, lane, s, spg);
    do_group<22, true >(1, apl, ring, lane, s, spg);
    do_group<28, true >(2, apl, ring, lane, s, spg);
    for (int g = 3; g <= 252; ++g)
        do_group<34, true >(g, apl, ring, lane, s, spg);
    do_group<34, false>(253, apl, ring, lane, s, spg);
    do_group<26, false>(254, apl, ring, lane, s, spg);
    do_group<18, false>(255, apl, ring, lane, s, spg);
}

// ---------------------------------------------------------------------------
// K3: out[b][t][:] = sig_row(24) @ softplus(W2)^T, chain-major sig reader,
// 1/sqrt(3) folded into the xy weight columns. One thread per (b,t);
// consecutive lanes = consecutive t -> each p-stream coalesced (12 B/lane).
// ---------------------------------------------------------------------------
__global__ __launch_bounds__(256) void k_out(
    const float* __restrict__ sig, const float* __restrict__ W2,
    float* __restrict__ out)
{
    __shared__ __align__(16) float4 w2v[48];   // [k][p] -> (w3p, w3p+1, w3p+2/sqrt3)
    int tid = threadIdx.x;
    if (tid < 48) {
        int k = tid >> 3, p = tid & 7;
        const float* wr = W2 + k * 24 + 3 * p;
        w2v[tid] = make_float4(softplus_f(wr[0]), softplus_f(wr[1]),
                               softplus_f(wr[2]) * IR3, 0.f);
    }
    __syncthreads();

    int gid = blockIdx.x * 256 + tid;          // = b*2048 + t
    int b = gid >> 11, t = gid & (TT - 1);

    float sx[8], sy[8], sz[8];
    #pragma unroll
    for (int p = 0; p < 8; ++p) {
        const float* cp = sig + (size_t)(b * 8 + p) * (TT * 3) + t * 3;
        sx[p] = cp[0]; sy[p] = cp[1]; sz[p] = cp[2];
    }
    float o[6];
    #pragma unroll
    for (int k = 0; k < 6; ++k) {
        float acc = 0.f;
        #pragma unroll
        for (int p = 0; p < 8; ++p) {
            float4 w = w2v[k * 8 + p];
            acc = fmaf(sx[p], w.x, acc);
            acc = fmaf(sy[p], w.y, acc);
            acc = fmaf(sz[p], w.z, acc);
        }
        o[k] = acc;
    }
    float2* ov = (float2*)(out + (size_t)gid * 6);
    ov[0] = make_float2(o[0], o[1]);
    ov[1] = make_float2(o[2], o[3]);
    ov[2] = make_float2(o[4], o[5]);
}

extern "C" void kernel_launch(void* const* d_in, const int* in_sizes, int n_in,
                              void* d_out, int out_size, void* d_ws, size_t ws_size,
                              hipStream_t stream)
{
    const float* x   = (const float*)d_in[0];
    const float* W11 = (const float*)d_in[1];
    const float* W12 = (const float*)d_in[2];
    const float* W2  = (const float*)d_in[3];
    float* out = (float*)d_out;

    float4* arr = (float4*)d_ws;                                    // 128 MiB
    float*  sig = (float*)((char*)d_ws + (size_t)TT * NCH * 16);    //  96 MiB

    hipLaunchKernelGGL(k_proj, dim3(BT * (TT / 32)), dim3(256), 0, stream,
                       x, W11, W12, arr);
    hipLaunchKernelGGL(k_scan, dim3(NCH / 64), dim3(64), 0, stream, arr, sig);
    hipLaunchKernelGGL(k_out,  dim3((BT * TT) / 256), dim3(256), 0, stream,
                       sig, W2, out);
}

// Round 10
// 178.812 us; speedup vs baseline: 2.1224x; 2.0345x over previous
//
#include <hip/hip_runtime.h>
#include <math.h>

static constexpr int BT  = 512;    // batch
static constexpr int TT  = 2048;   // time steps
static constexpr int NCH = BT * 8; // 4096 chains

// f64-derived constants, cast to f32 exactly as the reference does
static constexpr float C00 = (float)(1000.0 / (1.0 - 0.09));            // D[0][0]
static constexpr float C01 = (float)((1000.0 / (1.0 - 0.09)) * 0.3);    // D[0][1]
static constexpr float C22 = (float)((1000.0 / (1.0 - 0.09)) * 0.35);   // D[2][2]
static constexpr float INV3GH = (float)(1.0 / (3.0 * (1000.0 / 2.6) + 100.0));
static constexpr float SQ3 = 1.7320508075688772f;
static constexpr float IR3 = 0.57735026918962576f;

__device__ __forceinline__ float softplus_f(float v) {
    return fmaxf(v, 0.0f) + log1pf(expf(-fabsf(v)));
}

// ---------------------------------------------------------------------------
// K1: projections + damage candidate, coalesced via LDS x-tile.
// NEW output layout: arr[chain][t] float4 = (d_new, De_xx, De_yy, sqrt3*De_xy),
// chain = b*8+p.  (one wave of k_scan streams arr[chain][w*64..w*64+63].)
// ---------------------------------------------------------------------------
__global__ __launch_bounds__(256) void k_proj(
    const float* __restrict__ x, const float* __restrict__ W11,
    const float* __restrict__ W12, float4* __restrict__ arr)
{
    __shared__ __align__(16) float xs[32 * 36];    // [tl][36] padded
    __shared__ __align__(16) float w11s[16 * 36];  // [2p+h][36]
    __shared__ __align__(16) float w12d[24 * 36];  // [3p+j][36], D & sqrt3 folded
    const int tid = threadIdx.x;

    for (int i = tid; i < 512; i += 256)
        w11s[(i >> 5) * 36 + (i & 31)] = W11[i];
    for (int i = tid; i < 768; i += 256) {
        int r = i >> 5, fc = i & 31;
        int p = r / 3, j = r - p * 3;
        const float* wb = W12 + p * 96 + fc;
        float v;
        if (j == 0)      v = C00 * wb[0]  + C01 * wb[32];
        else if (j == 1) v = C01 * wb[0]  + C00 * wb[32];
        else             v = (C22 * wb[64]) * SQ3;
        w12d[r * 36 + fc] = v;
    }

    const int b  = blockIdx.x >> 6;
    const int tt = (blockIdx.x & 63) << 5;

    {
        const float4* xg = (const float4*)(x + ((size_t)b * TT + tt) * 32);
        float4 val = xg[tid];
        int tl = tid >> 3, c = tid & 7;
        *(float4*)&xs[tl * 36 + c * 4] = val;
    }
    __syncthreads();

    const int tl = tid >> 3, p = tid & 7;
    const float* xr = xs + tl * 36;
    const float4* wa0 = (const float4*)(w11s + (2 * p) * 36);
    const float4* wa1 = (const float4*)(w11s + (2 * p + 1) * 36);
    const float4* wb0 = (const float4*)(w12d + (3 * p) * 36);
    const float4* wb1 = (const float4*)(w12d + (3 * p + 1) * 36);
    const float4* wb2 = (const float4*)(w12d + (3 * p + 2) * 36);

    float dn = 0.f, ds = 0.f, e0 = 0.f, e1 = 0.f, e2 = 0.f;
    #pragma unroll
    for (int c = 0; c < 8; ++c) {
        float4 xf = *(const float4*)(xr + 4 * c);
        float4 a0 = wa0[c], a1 = wa1[c];
        float4 b0 = wb0[c], b1 = wb1[c], b2 = wb2[c];
        dn = fmaf(xf.x, a0.x, dn); dn = fmaf(xf.y, a0.y, dn);
        dn = fmaf(xf.z, a0.z, dn); dn = fmaf(xf.w, a0.w, dn);
        ds = fmaf(xf.x, a1.x, ds); ds = fmaf(xf.y, a1.y, ds);
        ds = fmaf(xf.z, a1.z, ds); ds = fmaf(xf.w, a1.w, ds);
        e0 = fmaf(xf.x, b0.x, e0); e0 = fmaf(xf.y, b0.y, e0);
        e0 = fmaf(xf.z, b0.z, e0); e0 = fmaf(xf.w, b0.w, e0);
        e1 = fmaf(xf.x, b1.x, e1); e1 = fmaf(xf.y, b1.y, e1);
        e1 = fmaf(xf.z, b1.z, e1); e1 = fmaf(xf.w, b1.w, e1);
        e2 = fmaf(xf.x, b2.x, e2); e2 = fmaf(xf.y, b2.y, e2);
        e2 = fmaf(xf.z, b2.z, e2); e2 = fmaf(xf.w, b2.w, e2);
    }
    float dnp = fmaxf(dn, 0.f);
    float lam = sqrtf(fmaf(dnp, dnp, fmaf(ds, ds, 1e-12f)));
    float dnew = (0.1f * (lam - 0.01f)) / (lam * 0.09f);
    dnew = fminf(fmaxf(dnew, 0.f), 1.f);

    arr[(size_t)(b * 8 + p) * TT + tt + tl] = make_float4(dnew, e0, e1, e2);
}

// ---------------------------------------------------------------------------
// K2: WINDOW-PARALLEL scan. One WAVE per chain (4096 waves = 16/CU).
// Per 64-step window: all lanes compute trial s,q under window-entry P;
// plastic events (ballot) are popped in t-order, each broadcasting the
// exact serial update; only lanes after the event recompute. Damage is an
// exclusive max-scan (associative -> shfl_up tree, bit-exact vs serial).
// sig layout [chain][t][3], xy sqrt3-scaled (k_out folds 1/sqrt3).
// ---------------------------------------------------------------------------
__global__ __launch_bounds__(64) void k_scan(
    const float4* __restrict__ arr, float* __restrict__ sig)
{
    const int lane  = threadIdx.x;
    const int chain = blockIdx.x;
    const float4* base = arr + (size_t)chain * TT;
    float* sp = sig + (size_t)chain * (TT * 3) + lane * 3;

    float Pxx = 0.f, Pyy = 0.f, Pxy = 0.f;
    float sigY = 10.f, sigY2 = 100.f, d0 = 0.f;

    float4 v = base[lane];
    for (int w = 0; w < 32; ++w) {
        const int wn = (w < 31) ? w + 1 : 31;
        float4 vn = base[wn * 64 + lane];

        float sxx = v.y - Pxx, syy = v.z - Pyy, sxy = v.w - Pxy;
        float q = fmaf(sxy, sxy, 1e-12f);   // sxy sqrt3-scaled
        q = fmaf(syy, syy, q);
        q = fmaf(sxx, sxx - syy, q);
        float f = 1.0f;

        unsigned long long mask = __ballot(q > sigY2);
        while (mask) {
            int ts = __ffsll((long long)mask) - 1;
            float qs  = __shfl(q, ts);
            float sxs = __shfl(sxx, ts);
            float sys = __shfl(syy, ts);
            float sps = __shfl(sxy, ts);
            float rq  = __builtin_amdgcn_rsqf(qs);
            float seq = qs * rq;
            float dk  = (seq - sigY) * INV3GH;      // > 0 at an event
            float fn  = fmaf(100.f, dk, sigY);      // new sigY
            float fs  = fn * rq;                    // < 1 at an event
            float om  = 1.0f - fs;
            Pxx = fmaf(om, sxs, Pxx);
            Pyy = fmaf(om, sys, Pyy);
            Pxy = fmaf(om, sps, Pxy);
            sigY = fn; sigY2 = fn * fn;
            if (lane == ts) f = fs;
            bool redo = lane > ts;
            if (redo) {
                sxx = v.y - Pxx; syy = v.z - Pyy; sxy = v.w - Pxy;
                q = fmaf(sxy, sxy, 1e-12f);
                q = fmaf(syy, syy, q);
                q = fmaf(sxx, sxx - syy, q);
            }
            mask = __ballot(redo && (q > sigY2));
        }

        // damage: exclusive max-scan over the window, seeded by d0
        float dn = v.x;
        float m = dn;
        #pragma unroll
        for (int off = 1; off < 64; off <<= 1) {
            float t2 = __shfl_up(m, off);
            if (lane >= off) m = fmaxf(m, t2);
        }
        float de = __shfl_up(m, 1);
        de = (lane == 0) ? d0 : fmaxf(d0, de);
        bool loading = dn > de;
        float di = fmaxf(de, dn);
        d0 = fmaxf(d0, __shfl(m, 63));

        float scale = loading ? f : f * (1.0f - di);
        sp[0] = scale * sxx;
        sp[1] = scale * syy;
        sp[2] = scale * sxy;
        sp += 192;      // 64 t's * 3 floats
        v = vn;
    }
}

// ---------------------------------------------------------------------------
// K3: out[b][t][:] = sig_row(24) @ softplus(W2)^T, chain-major sig reader,
// 1/sqrt(3) folded into the xy weight columns. One thread per (b,t).
// ---------------------------------------------------------------------------
__global__ __launch_bounds__(256) void k_out(
    const float* __restrict__ sig, const float* __restrict__ W2,
    float* __restrict__ out)
{
    __shared__ __align__(16) float4 w2v[48];   // [k][p]
    int tid = threadIdx.x;
    if (tid < 48) {
        int k = tid >> 3, p = tid & 7;
        const float* wr = W2 + k * 24 + 3 * p;
        w2v[tid] = make_float4(softplus_f(wr[0]), softplus_f(wr[1]),
                               softplus_f(wr[2]) * IR3, 0.f);
    }
    __syncthreads();

    int gid = blockIdx.x * 256 + tid;          // = b*2048 + t
    int b = gid >> 11, t = gid & (TT - 1);

    float sx[8], sy[8], sz[8];
    #pragma unroll
    for (int p = 0; p < 8; ++p) {
        const float* cp = sig + (size_t)(b * 8 + p) * (TT * 3) + t * 3;
        sx[p] = cp[0]; sy[p] = cp[1]; sz[p] = cp[2];
    }
    float o[6];
    #pragma unroll
    for (int k = 0; k < 6; ++k) {
        float acc = 0.f;
        #pragma unroll
        for (int p = 0; p < 8; ++p) {
            float4 w = w2v[k * 8 + p];
            acc = fmaf(sx[p], w.x, acc);
            acc = fmaf(sy[p], w.y, acc);
            acc = fmaf(sz[p], w.z, acc);
        }
        o[k] = acc;
    }
    float2* ov = (float2*)(out + (size_t)gid * 6);
    ov[0] = make_float2(o[0], o[1]);
    ov[1] = make_float2(o[2], o[3]);
    ov[2] = make_float2(o[4], o[5]);
}

extern "C" void kernel_launch(void* const* d_in, const int* in_sizes, int n_in,
                              void* d_out, int out_size, void* d_ws, size_t ws_size,
                              hipStream_t stream)
{
    const float* x   = (const float*)d_in[0];
    const float* W11 = (const float*)d_in[1];
    const float* W12 = (const float*)d_in[2];
    const float* W2  = (const float*)d_in[3];
    float* out = (float*)d_out;

    float4* arr = (float4*)d_ws;                                    // 128 MiB
    float*  sig = (float*)((char*)d_ws + (size_t)TT * NCH * 16);    //  96 MiB

    hipLaunchKernelGGL(k_proj, dim3(BT * (TT / 32)), dim3(256), 0, stream,
                       x, W11, W12, arr);
    hipLaunchKernelGGL(k_scan, dim3(NCH), dim3(64), 0, stream, arr, sig);
    hipLaunchKernelGGL(k_out,  dim3((BT * TT) / 256), dim3(256), 0, stream,
                       sig, W2, out);
}

// Round 11
// 154.222 us; speedup vs baseline: 2.4608x; 1.1594x over previous
//
#include <hip/hip_runtime.h>
#include <math.h>

static constexpr int BT  = 512;    // batch
static constexpr int TT  = 2048;   // time steps

// f64-derived constants, cast to f32 exactly as the reference does
static constexpr float C00 = (float)(1000.0 / (1.0 - 0.09));            // D[0][0]
static constexpr float C01 = (float)((1000.0 / (1.0 - 0.09)) * 0.3);    // D[0][1]
static constexpr float C22 = (float)((1000.0 / (1.0 - 0.09)) * 0.35);   // D[2][2]
static constexpr float INV3GH = (float)(1.0 / (3.0 * (1000.0 / 2.6) + 100.0));
static constexpr float SQ3 = 1.7320508075688772f;
static constexpr float IR3 = 0.57735026918962576f;

__device__ __forceinline__ float softplus_f(float v) {
    return fmaxf(v, 0.0f) + log1pf(expf(-fabsf(v)));
}

// ---------------------------------------------------------------------------
// Fully fused: projections + window-parallel scan + W2 output, one kernel.
// Block = one b (512 threads = 8 waves); wave = p (chain b*8+p); lane = t.
// Per 64-t window:
//   - x[b] window staged in LDS (double-buffered, [64][36] pad, coalesced)
//   - wave p projects (W11/W12·D rows are wave-uniform -> LDS broadcasts)
//   - R10's verified ballot plastic scan + shfl damage max-scan (registers)
//   - wave p folds its 3 stress comps through W2 cols -> 6 partials -> LDS
//   - 384 threads reduce over p and store out[b][t][k] directly.
// Eliminates the arr (256 MiB) and sig (192 MiB) round-trips entirely.
// ---------------------------------------------------------------------------
__global__ __launch_bounds__(512) void k_fused(
    const float* __restrict__ x, const float* __restrict__ W11,
    const float* __restrict__ W12, const float* __restrict__ W2,
    float* __restrict__ out)
{
    __shared__ __align__(16) float w11s[16 * 36];   // [2p+h][36]
    __shared__ __align__(16) float w12d[24 * 36];   // [3p+j][36], D & sqrt3 folded
    __shared__ float w2s[144];                      // softplus(W2), xy col /sqrt3
    __shared__ __align__(16) float xs[2][64 * 36];  // double-buffered x window
    __shared__ float red[64 * 51];                  // [t][k*8+p] partials

    const int tid  = threadIdx.x;
    const int lane = tid & 63;     // t within window
    const int wv   = tid >> 6;     // p (0..7)
    const int b    = blockIdx.x;

    // ---- prologue: weights into LDS ----
    if (tid < 512) w11s[(tid >> 5) * 36 + (tid & 31)] = W11[tid];
    if (tid < 256) {
        int i = tid + 512;
        w11s[(i >> 5) * 36 + (i & 31)] = W11[i];
    }
    for (int i = tid; i < 768; i += 512) {
        int r = i >> 5, fc = i & 31;
        int p = r / 3, j = r - p * 3;
        const float* wb = W12 + p * 96 + fc;
        float v;
        if (j == 0)      v = C00 * wb[0]  + C01 * wb[32];
        else if (j == 1) v = C01 * wb[0]  + C00 * wb[32];
        else             v = (C22 * wb[64]) * SQ3;
        w12d[r * 36 + fc] = v;
    }
    if (tid < 144) {
        float v = softplus_f(W2[tid]);
        if ((tid % 24) % 3 == 2) v *= IR3;
        w2s[tid] = v;
    }
    // stage window 0
    const float4* xg4 = (const float4*)x + (size_t)b * (TT * 8);
    {
        float4 val = xg4[tid];
        int t = tid >> 3, c = tid & 7;
        *(float4*)&xs[0][t * 36 + 4 * c] = val;
    }
    __syncthreads();

    // wave-uniform W2 columns for this p
    float w2r0[6], w2r1[6], w2r2[6];
    #pragma unroll
    for (int k = 0; k < 6; ++k) {
        w2r0[k] = w2s[k * 24 + 3 * wv];
        w2r1[k] = w2s[k * 24 + 3 * wv + 1];
        w2r2[k] = w2s[k * 24 + 3 * wv + 2];
    }
    const float4* wa0 = (const float4*)(w11s + (2 * wv) * 36);
    const float4* wa1 = (const float4*)(w11s + (2 * wv + 1) * 36);
    const float4* wb0 = (const float4*)(w12d + (3 * wv) * 36);
    const float4* wb1 = (const float4*)(w12d + (3 * wv + 1) * 36);
    const float4* wb2 = (const float4*)(w12d + (3 * wv + 2) * 36);

    float Pxx = 0.f, Pyy = 0.f, Pxy = 0.f;
    float sigY = 10.f, sigY2 = 100.f, d0 = 0.f;

    for (int w = 0; w < 32; ++w) {
        // issue next window's x load early (latency hides under compute)
        float4 nval;
        const bool have = (w < 31);
        if (have) nval = xg4[(w + 1) * 512 + tid];

        // ---- projection for (chain b*8+wv, t = w*64+lane) ----
        const float* xr = &xs[w & 1][lane * 36];
        float dn = 0.f, ds = 0.f, e0 = 0.f, e1 = 0.f, e2 = 0.f;
        #pragma unroll
        for (int c = 0; c < 8; ++c) {
            float4 xf = *(const float4*)(xr + 4 * c);
            float4 a0 = wa0[c], a1 = wa1[c];
            float4 b0 = wb0[c], b1 = wb1[c], b2 = wb2[c];
            dn = fmaf(xf.x, a0.x, dn); dn = fmaf(xf.y, a0.y, dn);
            dn = fmaf(xf.z, a0.z, dn); dn = fmaf(xf.w, a0.w, dn);
            ds = fmaf(xf.x, a1.x, ds); ds = fmaf(xf.y, a1.y, ds);
            ds = fmaf(xf.z, a1.z, ds); ds = fmaf(xf.w, a1.w, ds);
            e0 = fmaf(xf.x, b0.x, e0); e0 = fmaf(xf.y, b0.y, e0);
            e0 = fmaf(xf.z, b0.z, e0); e0 = fmaf(xf.w, b0.w, e0);
            e1 = fmaf(xf.x, b1.x, e1); e1 = fmaf(xf.y, b1.y, e1);
            e1 = fmaf(xf.z, b1.z, e1); e1 = fmaf(xf.w, b1.w, e1);
            e2 = fmaf(xf.x, b2.x, e2); e2 = fmaf(xf.y, b2.y, e2);
            e2 = fmaf(xf.z, b2.z, e2); e2 = fmaf(xf.w, b2.w, e2);
        }
        float dnp  = fmaxf(dn, 0.f);
        float lam  = sqrtf(fmaf(dnp, dnp, fmaf(ds, ds, 1e-12f)));
        float dnew = (0.1f * (lam - 0.01f)) / (lam * 0.09f);
        dnew = fminf(fmaxf(dnew, 0.f), 1.f);

        // ---- window-parallel plastic scan (verified R10 flow) ----
        float sxx = e0 - Pxx, syy = e1 - Pyy, sxy = e2 - Pxy;
        float q = fmaf(sxy, sxy, 1e-12f);   // sxy sqrt3-scaled
        q = fmaf(syy, syy, q);
        q = fmaf(sxx, sxx - syy, q);
        float f = 1.0f;

        unsigned long long mask = __ballot(q > sigY2);
        while (mask) {
            int ts = __ffsll((long long)mask) - 1;
            float qs  = __shfl(q, ts);
            float sxs = __shfl(sxx, ts);
            float sys = __shfl(syy, ts);
            float sps = __shfl(sxy, ts);
            float rq  = __builtin_amdgcn_rsqf(qs);
            float seq = qs * rq;
            float dk  = (seq - sigY) * INV3GH;
            float fn  = fmaf(100.f, dk, sigY);
            float fs  = fn * rq;
            float om  = 1.0f - fs;
            Pxx = fmaf(om, sxs, Pxx);
            Pyy = fmaf(om, sys, Pyy);
            Pxy = fmaf(om, sps, Pxy);
            sigY = fn; sigY2 = fn * fn;
            if (lane == ts) f = fs;
            bool redo = lane > ts;
            if (redo) {
                sxx = e0 - Pxx; syy = e1 - Pyy; sxy = e2 - Pxy;
                q = fmaf(sxy, sxy, 1e-12f);
                q = fmaf(syy, syy, q);
                q = fmaf(sxx, sxx - syy, q);
            }
            mask = __ballot(redo && (q > sigY2));
        }

        // damage: exclusive max-scan seeded by d0
        float m = dnew;
        #pragma unroll
        for (int off = 1; off < 64; off <<= 1) {
            float t2 = __shfl_up(m, off);
            if (lane >= off) m = fmaxf(m, t2);
        }
        float de = __shfl_up(m, 1);
        de = (lane == 0) ? d0 : fmaxf(d0, de);
        bool loading = dnew > de;
        float di = fmaxf(de, dnew);
        d0 = fmaxf(d0, __shfl(m, 63));

        float scale = loading ? f : f * (1.0f - di);
        float o0 = scale * sxx, o1 = scale * syy, o2 = scale * sxy;

        // write next window's stage (disjoint buffer; guarded by prev barrier)
        if (have) {
            int t = tid >> 3, c = tid & 7;
            *(float4*)&xs[(w + 1) & 1][t * 36 + 4 * c] = nval;
        }

        // ---- per-wave W2 partials -> red[t][k*8+p] ----
        #pragma unroll
        for (int k = 0; k < 6; ++k) {
            float cpk = fmaf(o0, w2r0[k], fmaf(o1, w2r1[k], o2 * w2r2[k]));
            red[lane * 51 + k * 8 + wv] = cpk;
        }
        __syncthreads();

        // ---- reduce over p and store out ----
        if (tid < 384) {
            int t = tid & 63, k = tid >> 6;
            const float* rp = &red[t * 51 + k * 8];
            float acc = ((rp[0] + rp[1]) + (rp[2] + rp[3]))
                      + ((rp[4] + rp[5]) + (rp[6] + rp[7]));
            out[((size_t)b * TT + w * 64 + t) * 6 + k] = acc;
        }
        __syncthreads();   // red free + xs[(w+1)&1] ready for next window
    }
}

extern "C" void kernel_launch(void* const* d_in, const int* in_sizes, int n_in,
                              void* d_out, int out_size, void* d_ws, size_t ws_size,
                              hipStream_t stream)
{
    const float* x   = (const float*)d_in[0];
    const float* W11 = (const float*)d_in[1];
    const float* W12 = (const float*)d_in[2];
    const float* W2  = (const float*)d_in[3];
    float* out = (float*)d_out;

    hipLaunchKernelGGL(k_fused, dim3(BT), dim3(512), 0, stream,
                       x, W11, W12, W2, out);
}